// Round 5
// baseline (320.810 us; speedup 1.0000x reference)
//
#include <hip/hip_runtime.h>

// WaveConv1d on MI355X — round 16: einsum_v10 (barrier-free, LDS-free).
//   out = x + idwt(E1(lo4)-lo4, E2(h4)-h4, 0, 0, 0)
// r15 post-mortem: v5/v6/v8/v9 — five schedules (sync, deep-async, contiguous
// requests) all 113-160us, every pipe <50%, FETCH < w-size (L3 retains w).
// H1 (request size) falsified. H2: the barrier-per-chunk structure itself is
// the limiter (phase-aligned waves, per-chunk critical path). The einsum is
// k-pointwise => a wave can own (16b x 4o x 64k) and run the whole i-reduction
// privately: v10 has ZERO LDS, ZERO barriers. xT re-laid as [c][k][b16] so a
// lane reads its 16 b as two dwordx4 (32B contiguous); w = 4 coalesced dwords
// per wave per i; i split 8-ways (atomicAdd into zeroed dlo/dh); grid encoded
// so the 16 blocks sharing an x-slice land on one XCD; 2-deep register
// ping-pong prefetch (named regs, no arrays -> no spill).

#define NROWS 4096          // B*C
#define MODES 522

#define M1 4101
#define M2 2056
#define M3 1033
#define M4 522

typedef unsigned int  uint;
typedef unsigned short ushort;

__constant__ float c_dlo[12] = {
  -0.00107730108499558f,  0.004777257511010651f,  0.0005538422009938016f,
  -0.031582039318031156f, 0.02752286553001629f,   0.09750160558707936f,
  -0.12976686756709563f,  -0.22626469396516913f,  0.3152503517092432f,
   0.7511339080215775f,   0.4946238903983854f,    0.11154074335008017f };
__constant__ float c_dhi[12] = {
  -0.11154074335008017f,  0.4946238903983854f,   -0.7511339080215775f,
   0.3152503517092432f,   0.22626469396516913f,  -0.12976686756709563f,
  -0.09750160558707936f,  0.02752286553001629f,   0.031582039318031156f,
   0.0005538422009938016f,-0.004777257511010651f, -0.00107730108499558f };
// Analysis (time-reversed) filters
__constant__ float c_alo[12] = {
   0.11154074335008017f,  0.4946238903983854f,    0.7511339080215775f,
   0.3152503517092432f,  -0.22626469396516913f,  -0.12976686756709563f,
   0.09750160558707936f,  0.02752286553001629f,  -0.031582039318031156f,
   0.0005538422009938016f, 0.004777257511010651f, -0.00107730108499558f };
__constant__ float c_ahi[12] = {
  -0.00107730108499558f, -0.004777257511010651f,  0.0005538422009938016f,
   0.031582039318031156f, 0.02752286553001629f,  -0.09750160558707936f,
  -0.12976686756709563f,  0.22626469396516913f,   0.3152503517092432f,
  -0.7511339080215775f,   0.4946238903983854f,   -0.11154074335008017f };

__device__ __forceinline__ ushort f2bf(float f) {
    uint b = __float_as_uint(f);
    uint r = (b + 0x7fffu + ((b >> 16) & 1u)) >> 16;
    return (ushort)r;
}

// One lo-only analysis level LDS->LDS, interior fast path (no reflect).
__device__ __forceinline__
void dwt_lo_lds(const float* __restrict__ src, int n, int m,
                float* __restrict__ dst, int tid)
{
    int jhi = (n - 2) >> 1;
    for (int j = tid; j < m; j += 256) {
        float a = 0.f;
        if (j >= 5 && j <= jhi) {
            const float* s = src + 2 * j - 10;
#pragma unroll
            for (int t = 0; t < 12; ++t) a += s[t] * c_alo[t];
        } else {
            int base = 2 * j - 10;
#pragma unroll
            for (int t = 0; t < 12; ++t) {
                int u = base + t;
                u = (u < 0) ? (-1 - u) : u;
                u = (u >= n) ? (2 * n - 1 - u) : u;
                a += src[u] * c_alo[t];
            }
        }
        dst[j] = a;
    }
}

// Fused forward DWT, lo-chain only: x -> (lo4, h4). One block per row.
__global__ __launch_bounds__(256)
void dwt_fused2(const float* __restrict__ x,
                float* __restrict__ lo4g, float* __restrict__ h4g)
{
    __shared__ float X[8192];
    __shared__ float LA[4104];
    int row = blockIdx.x, tid = threadIdx.x;

    const float4* xr = (const float4*)(x + (size_t)row * 8192);
    float4* Xv = (float4*)X;
#pragma unroll
    for (int i = 0; i < 8; ++i) Xv[tid + 256 * i] = xr[tid + 256 * i];
    __syncthreads();

    dwt_lo_lds(X,  8192, M1, LA, tid);
    __syncthreads();
    dwt_lo_lds(LA, M1,   M2, X,  tid);
    __syncthreads();
    dwt_lo_lds(X,  M2,   M3, LA, tid);
    __syncthreads();

    float* lo4r = lo4g + (size_t)row * M4;
    float* h4r  = h4g  + (size_t)row * M4;
    int jhi = (M3 - 2) >> 1;
    for (int j = tid; j < M4; j += 256) {
        float alo = 0.f, ahi = 0.f;
        if (j >= 5 && j <= jhi) {
            const float* s = LA + 2 * j - 10;
#pragma unroll
            for (int t = 0; t < 12; ++t) {
                float v = s[t];
                alo += v * c_alo[t]; ahi += v * c_ahi[t];
            }
        } else {
            int base = 2 * j - 10;
#pragma unroll
            for (int t = 0; t < 12; ++t) {
                int u = base + t;
                u = (u < 0) ? (-1 - u) : u;
                u = (u >= M3) ? (2 * M3 - 1 - u) : u;
                float v = LA[u];
                alo += v * c_alo[t]; ahi += v * c_ahi[t];
            }
        }
        lo4r[j] = alo; h4r[j] = ahi;
    }
}

// xpose3: [b][c][k] fp32 -> bf16 xT [c][k=522][b16] (16 contiguous b per
// (c,k), 32 B). One block per (c, tensor). ALSO zero-fills dlo/dh for
// einsum_v10's atomicAdd accumulation.
__global__ __launch_bounds__(256)
void xpose3(const float* __restrict__ lo4, const float* __restrict__ h4,
            ushort* __restrict__ xlT, ushort* __restrict__ xhT,
            float* __restrict__ dzero)
{
    __shared__ float L[16][528];
    int c = blockIdx.x;
    const float* src = blockIdx.y ? h4 : lo4;
    ushort*      dst = blockIdx.y ? xhT : xlT;
    int t = threadIdx.x;

    // zero dlo+dh: 2*SZ floats over 512 blocks x 256 thr
    {
        const size_t nz = ((size_t)2 * NROWS * M4) / 4;
        size_t gid = ((size_t)blockIdx.y * gridDim.x + blockIdx.x) * 256 + t;
        float4 z4 = make_float4(0.f, 0.f, 0.f, 0.f);
        float4* zp = (float4*)dzero;
        for (size_t i = gid; i < nz; i += (size_t)512 * 256) zp[i] = z4;
    }

#pragma unroll
    for (int b = 0; b < 16; ++b)
        for (int k = t; k < MODES; k += 256)
            L[b][k] = src[((size_t)b * 256 + c) * MODES + k];
    __syncthreads();

    for (int k = t; k < MODES; k += 256) {
#pragma unroll
        for (int g = 0; g < 4; ++g) {
            ushort4 v;
            v.x = f2bf(L[4*g+0][k]);
            v.y = f2bf(L[4*g+1][k]);
            v.z = f2bf(L[4*g+2][k]);
            v.w = f2bf(L[4*g+3][k]);
            *(ushort4*)&dst[((size_t)c * MODES + k) * 16 + 4 * g] = v;
        }
    }
}

// Delta-IDWT: A = dlo-lo4, Hs = dh-h4; lvl4 full -> lvl3,2,1 lo-only -> +x.
__global__ __launch_bounds__(256)
void idwt_delta2(const float* __restrict__ dlo, const float* __restrict__ dh,
                 const float* __restrict__ lo4, const float* __restrict__ h4,
                 const float* __restrict__ x,   float* __restrict__ out)
{
    __shared__ float A[2056];
    __shared__ float B[4104];
    __shared__ float Hs[528];
    int row = blockIdx.x, tid = threadIdx.x;

    for (int i = tid; i < M4; i += 256) {
        size_t idx = (size_t)row * M4 + i;
        A[i]  = dlo[idx] - lo4[idx];
        Hs[i] = dh[idx]  - h4[idx];
    }
    __syncthreads();

    for (int jj = tid; jj < M4 - 5; jj += 256) {
        float e = 0.f, od = 0.f;
#pragma unroll
        for (int s = 0; s < 6; ++s) {
            float xv = A[jj + s], hv = Hs[jj + s];
            e  += xv * c_dlo[2*s+1] + hv * c_dhi[2*s+1];
            od += xv * c_dlo[2*s]   + hv * c_dhi[2*s];
        }
        B[2*jj] = e; B[2*jj+1] = od;
    }
    __syncthreads();

    for (int jj = tid; jj < M3 - 5; jj += 256) {
        float e = 0.f, od = 0.f;
#pragma unroll
        for (int s = 0; s < 6; ++s) {
            float xv = B[jj + s];
            e  += xv * c_dlo[2*s+1];
            od += xv * c_dlo[2*s];
        }
        A[2*jj] = e; A[2*jj+1] = od;
    }
    __syncthreads();

    for (int jj = tid; jj < M2 - 5; jj += 256) {
        float e = 0.f, od = 0.f;
#pragma unroll
        for (int s = 0; s < 6; ++s) {
            float xv = A[jj + s];
            e  += xv * c_dlo[2*s+1];
            od += xv * c_dlo[2*s];
        }
        B[2*jj] = e; B[2*jj+1] = od;
    }
    __syncthreads();

    const float2* x2 = (const float2*)(x + (size_t)row * 8192);
    float2* o2 = (float2*)(out + (size_t)row * 8192);
    for (int jj = tid; jj < M1 - 5; jj += 256) {
        float e = 0.f, od = 0.f;
#pragma unroll
        for (int s = 0; s < 6; ++s) {
            float xv = B[jj + s];
            e  += xv * c_dlo[2*s+1];
            od += xv * c_dlo[2*s];
        }
        float2 xv2 = x2[jj];
        o2[jj] = make_float2(xv2.x + e, xv2.y + od);
    }
}

// Dual einsum v10: barrier-free, LDS-free. Wave owns (16b x 4o x 64k),
// private i-reduction over 32 i; 8 i-quarters combined via atomicAdd.
// Grid 2304 = 9 ks x 16 t x 16 lo; bid = ks*256 + t*16 + lo.
//   lo = e*8 + iq  (bid%8 const across the 16 t-blocks sharing an x-slice
//   -> same XCD under round-robin dispatch; perf-only heuristic).
//   oq = t*4 + wv; o = 4*oq; ks<8: kbase=ks*64; ks=8: kbase=458 (stores
//   masked to lane>=54 i.e. k>=512 to avoid double-count with ks=7).
// Per wave per i: x = 2 dwordx4 (32B contiguous, xT[c][k][b16]);
// w = 4 coalesced dwords (lane=k). acc[16][4]; 2-deep named-reg ping-pong.
__global__ __launch_bounds__(256)
void einsum_v10(const ushort* __restrict__ xlT, const ushort* __restrict__ xhT,
                const float* __restrict__ w1,   const float* __restrict__ w2,
                float* __restrict__ dlo, float* __restrict__ dh)
{
    int bid = blockIdx.x;
    int lo  = bid & 15;
    int t   = (bid >> 4) & 15;
    int ks  = bid >> 8;            // 0..8
    int e   = lo >> 3;
    int iq  = lo & 7;

    const ushort* xT = e ? xhT : xlT;
    const float*  w  = e ? w2  : w1;
    float* outp      = e ? dh  : dlo;

    int lane = threadIdx.x & 63;
    int wv   = threadIdx.x >> 6;
    int oq   = t * 4 + wv;
    int o    = oq * 4;
    int kbase = (ks < 8) ? ks * 64 : (MODES - 64);
    int i0   = iq * 32;

    const size_t XI = (size_t)MODES * 16;      // ushorts per i
    const size_t WI = (size_t)256 * MODES;     // floats per i

    const ushort* xb  = xT + ((size_t)i0 * MODES + kbase + lane) * 16;
    const float*  w0p = w  + ((size_t)i0 * 256 + o) * MODES + kbase + lane;
    const float*  w2p = w0p + 2 * MODES;

    float acc[16][4];
#pragma unroll
    for (int b = 0; b < 16; ++b)
#pragma unroll
        for (int j = 0; j < 4; ++j) acc[b][j] = 0.f;

    uint4 xa0, xa1, xc0, xc1;
    float fa0, fa1, fa2, fa3, fc0, fc1, fc2, fc3;

#define LOADA(I) do {                                                         \
    const ushort* xp_ = xb + (size_t)(I) * XI;                                \
    xa0 = *(const uint4*)xp_; xa1 = *(const uint4*)(xp_ + 8);                 \
    const float* wp_ = w0p + (size_t)(I) * WI;                                \
    fa0 = wp_[0]; fa1 = wp_[MODES];                                           \
    const float* wq_ = w2p + (size_t)(I) * WI;                                \
    fa2 = wq_[0]; fa3 = wq_[MODES];                                           \
} while (0)

#define LOADC(I) do {                                                         \
    const ushort* xp_ = xb + (size_t)(I) * XI;                                \
    xc0 = *(const uint4*)xp_; xc1 = *(const uint4*)(xp_ + 8);                 \
    const float* wp_ = w0p + (size_t)(I) * WI;                                \
    fc0 = wp_[0]; fc1 = wp_[MODES];                                           \
    const float* wq_ = w2p + (size_t)(I) * WI;                                \
    fc2 = wq_[0]; fc3 = wq_[MODES];                                           \
} while (0)

#define EMIT(BB, V) { float xv_ = __uint_as_float(V);                         \
    acc[BB][0] += xv_ * g0; acc[BB][1] += xv_ * g1;                           \
    acc[BB][2] += xv_ * g2; acc[BB][3] += xv_ * g3; }

#define COMP(U0, U1, F0, F1, F2, F3) do {                                     \
    float g0 = (F0), g1 = (F1), g2 = (F2), g3 = (F3);                         \
    EMIT(0,  (U0).x << 16)        EMIT(1,  (U0).x & 0xffff0000u)              \
    EMIT(2,  (U0).y << 16)        EMIT(3,  (U0).y & 0xffff0000u)              \
    EMIT(4,  (U0).z << 16)        EMIT(5,  (U0).z & 0xffff0000u)              \
    EMIT(6,  (U0).w << 16)        EMIT(7,  (U0).w & 0xffff0000u)              \
    EMIT(8,  (U1).x << 16)        EMIT(9,  (U1).x & 0xffff0000u)              \
    EMIT(10, (U1).y << 16)        EMIT(11, (U1).y & 0xffff0000u)              \
    EMIT(12, (U1).z << 16)        EMIT(13, (U1).z & 0xffff0000u)              \
    EMIT(14, (U1).w << 16)        EMIT(15, (U1).w & 0xffff0000u)              \
} while (0)

    LOADA(0);
    LOADC(1);
    for (int m = 0; m < 15; ++m) {
        COMP(xa0, xa1, fa0, fa1, fa2, fa3);
        LOADA(2 * m + 2);
        COMP(xc0, xc1, fc0, fc1, fc2, fc3);
        LOADC(2 * m + 3);
    }
    COMP(xa0, xa1, fa0, fa1, fa2, fa3);
    COMP(xc0, xc1, fc0, fc1, fc2, fc3);

#undef LOADA
#undef LOADC
#undef EMIT
#undef COMP

    // atomic accumulate (8 iq-parts per element).
    // ks=8 overlaps ks=7 for k in [458,512): only lanes with k>=512 write.
    bool wrk = (ks < 8) || (lane >= 54);
    if (wrk) {
#pragma unroll
        for (int b = 0; b < 16; ++b)
#pragma unroll
            for (int j = 0; j < 4; ++j)
                atomicAdd(&outp[((size_t)(b * 256 + o + j)) * MODES + kbase + lane],
                          acc[b][j]);
    }
}

extern "C" void kernel_launch(void* const* d_in, const int* in_sizes, int n_in,
                              void* d_out, int out_size, void* d_ws, size_t ws_size,
                              hipStream_t stream)
{
    const float* x  = (const float*)d_in[0];
    const float* w1 = (const float*)d_in[1];
    const float* w2 = (const float*)d_in[2];
    float* out = (float*)d_out;
    float* ws  = (float*)d_ws;

    const size_t SZ = (size_t)NROWS * M4;   // 2,138,112
    float* lo4 = ws;
    float* h4  = lo4 + SZ;
    float* dlo = h4  + SZ;
    float* dh  = dlo + SZ;                   // dlo,dh contiguous (zeroed together)
    ushort* xlT = (ushort*)(dh + SZ);        // SZ*16/... xT = 256*522*16 ushorts
    ushort* xhT = xlT + (size_t)256 * MODES * 16;

    dim3 blk(256);

    dwt_fused2<<<NROWS, blk, 0, stream>>>(x, lo4, h4);
    xpose3<<<dim3(256, 2), blk, 0, stream>>>(lo4, h4, xlT, xhT, dlo);
    einsum_v10<<<2304, blk, 0, stream>>>(xlT, xhT, w1, w2, dlo, dh);
    idwt_delta2<<<NROWS, blk, 0, stream>>>(dlo, dh, lo4, h4, x, out);
}